// Round 1
// baseline (244.967 us; speedup 1.0000x reference)
//
#include <hip/hip_runtime.h>

// DualModeSinkhorn, N_STREAMS=2, SINKHORN_ITER=20.
// The scan body is linear per (b,h,w): row step x[i][j] -> -x[i][1-j],
// col step y[i][j] -> -y[1-i][j]; composed: x[i][j] -> x[1-i][1-j], an
// involution. 20 (even) iterations == identity, so output = exp(input)
// elementwise. Memory-bound: 302 MB traffic -> ~50 us floor.

__global__ void __launch_bounds__(256)
exp_vec4_kernel(const float4* __restrict__ in, float4* __restrict__ out, int n4) {
    int idx = blockIdx.x * blockDim.x + threadIdx.x;
    if (idx < n4) {
        float4 v = in[idx];
        float4 r;
        r.x = __expf(v.x);
        r.y = __expf(v.y);
        r.z = __expf(v.z);
        r.w = __expf(v.w);
        out[idx] = r;
    }
}

__global__ void __launch_bounds__(64)
exp_tail_kernel(const float* __restrict__ in, float* __restrict__ out,
                int start, int n) {
    int idx = start + blockIdx.x * blockDim.x + threadIdx.x;
    if (idx < n) {
        out[idx] = __expf(in[idx]);
    }
}

extern "C" void kernel_launch(void* const* d_in, const int* in_sizes, int n_in,
                              void* d_out, int out_size, void* d_ws, size_t ws_size,
                              hipStream_t stream) {
    const float* in = (const float*)d_in[0];
    float* out = (float*)d_out;
    int n = out_size;                 // == in_sizes[0] == 16*4*768*768
    int n4 = n / 4;

    if (n4 > 0) {
        int blocks = (n4 + 255) / 256;
        exp_vec4_kernel<<<blocks, 256, 0, stream>>>(
            (const float4*)in, (float4*)out, n4);
    }
    int rem = n - n4 * 4;
    if (rem > 0) {
        exp_tail_kernel<<<1, 64, 0, stream>>>(in, out, n4 * 4, n);
    }
}